// Round 15
// baseline (47.952 us; speedup 1.0000x reference)
//
#include <hip/hip_runtime.h>
#include <hip/hip_bf16.h>
#include <math.h>

#define BB 2
#define NN 2048
#define FF 128
#define HH 4
#define HALF 1024

typedef __attribute__((ext_vector_type(8))) short short8;
typedef __attribute__((ext_vector_type(4))) short short4v;
typedef __attribute__((ext_vector_type(2))) short short2v;
typedef __attribute__((ext_vector_type(4))) float f32x4;

__device__ __forceinline__ short f2bf(float f){
    __hip_bfloat16 h = __float2bfloat16(f);
    return *reinterpret_cast<short*>(&h);
}
__device__ __forceinline__ float bf2f(short v){
    __hip_bfloat16 h = *reinterpret_cast<__hip_bfloat16*>(&v);
    return __bfloat162float(h);
}

// K1: x @ W[h] via MFMA -> WhB (bf16 B-fragment layout, UNSCALED) + sT/dT + denom zero.
// grid (32, 4, 2), block 256 = 4 waves (wm=w>>1, wn=w&1). (verbatim)
__global__ __launch_bounds__(256) void k_whmm(const float* __restrict__ x,
        const float* __restrict__ W, const float* __restrict__ a,
        short* __restrict__ WhB, float* __restrict__ sT, float* __restrict__ dT,
        float* __restrict__ denom){
    __shared__ short xs[64 * 136];
    __shared__ short ws_[128 * 130];
    __shared__ float red_s[2][64], red_d[2][64];
    int t = threadIdx.x;
    int w = t >> 6, lane = t & 63;
    int wm = w >> 1, wn = w & 1;
    int n0 = blockIdx.x * 64;
    int h = blockIdx.y, b = blockIdx.z;
    int sl = b * HH + h;
    int flat = blockIdx.x + 32 * (blockIdx.y + HH * blockIdx.z);
    if(t < 64) denom[flat * 64 + t] = 0.f;
    const float* xb = x + ((size_t)b * NN + n0) * FF;
    #pragma unroll
    for(int l = 0; l < 8; l++){
        int flat4 = t + l * 256;
        int row = flat4 >> 5, col4 = flat4 & 31;
        float4 v = *(const float4*)(xb + (size_t)row * FF + col4 * 4);
        short* dst = &xs[row * 136 + col4 * 4];
        dst[0] = f2bf(v.x); dst[1] = f2bf(v.y); dst[2] = f2bf(v.z); dst[3] = f2bf(v.w);
    }
    const float* Wb = W + (size_t)h * FF * FF;
    #pragma unroll
    for(int l = 0; l < 16; l++){
        int flat4 = t + l * 256;
        int row = flat4 >> 5, col4 = flat4 & 31;
        float4 v = *(const float4*)(Wb + (size_t)row * FF + col4 * 4);
        short* dst = &ws_[row * 130 + col4 * 4];
        dst[0] = f2bf(v.x); dst[1] = f2bf(v.y); dst[2] = f2bf(v.z); dst[3] = f2bf(v.w);
    }
    __syncthreads();
    int m = lane & 15, q = lane >> 4;
    f32x4 acc[2][4] = {};
    #pragma unroll
    for(int ks = 0; ks < 4; ks++){
        short8 af[2];
        #pragma unroll
        for(int mi = 0; mi < 2; mi++)
            af[mi] = *(const short8*)&xs[(wm * 32 + mi * 16 + m) * 136 + ks * 32 + q * 8];
        short8 bf[4];
        #pragma unroll
        for(int ni = 0; ni < 4; ni++){
            #pragma unroll
            for(int e = 0; e < 8; e++)
                bf[ni][e] = ws_[(ks * 32 + q * 8 + e) * 130 + wn * 64 + ni * 16 + m];
        }
        #pragma unroll
        for(int mi = 0; mi < 2; mi++)
            #pragma unroll
            for(int ni = 0; ni < 4; ni++)
                acc[mi][ni] = __builtin_amdgcn_mfma_f32_16x16x32_bf16(af[mi], bf[ni], acc[mi][ni], 0, 0, 0);
    }
    float asrc[4], adst[4];
    const float* ah = a + (size_t)h * 2 * FF;
    #pragma unroll
    for(int ni = 0; ni < 4; ni++){
        int col = wn * 64 + ni * 16 + m;
        asrc[ni] = ah[col];
        adst[ni] = ah[FF + col];
    }
    #pragma unroll
    for(int mi = 0; mi < 2; mi++){
        #pragma unroll
        for(int rg = 0; rg < 4; rg++){
            float ps = 0.f, pd = 0.f;
            #pragma unroll
            for(int ni = 0; ni < 4; ni++){
                ps += acc[mi][ni][rg] * asrc[ni];
                pd += acc[mi][ni][rg] * adst[ni];
            }
            #pragma unroll
            for(int msk = 8; msk >= 1; msk >>= 1){
                ps += __shfl_xor(ps, msk);
                pd += __shfl_xor(pd, msk);
            }
            if(m == 0){
                int row = wm * 32 + mi * 16 + q * 4 + rg;
                red_s[wn][row] = ps;
                red_d[wn][row] = pd;
            }
        }
    }
    __syncthreads();
    short* cs = xs;
    #pragma unroll
    for(int mi = 0; mi < 2; mi++){
        #pragma unroll
        for(int ni = 0; ni < 4; ni++){
            int col = wn * 64 + ni * 16 + m;
            #pragma unroll
            for(int rg = 0; rg < 4; rg++){
                int row = wm * 32 + mi * 16 + q * 4 + rg;
                cs[row * 130 + col] = f2bf(acc[mi][ni][rg]);
            }
        }
    }
    if(t < 64){
        int n = n0 + t;
        sT[((size_t)b * NN + n) * HH + h] = red_s[0][t] + red_s[1][t];
        dT[((size_t)b * NN + n) * HH + h] = red_d[0][t] + red_d[1][t];
    }
    __syncthreads();
    #pragma unroll
    for(int fi = 0; fi < 4; fi++){
        int fragId = w * 4 + fi;
        int ktg = fragId >> 3, nt = fragId & 7;
        short8 pk;
        #pragma unroll
        for(int e = 0; e < 8; e++)
            pk[e] = cs[(ktg * 32 + q * 8 + e) * 130 + nt * 16 + m];
        *(short8*)(WhB + (((size_t)sl * 8 + nt) * 64 + blockIdx.x * 2 + ktg) * 512 + lane * 8) = pk;
    }
}

// K2: ROW-MAJOR streaming attention, 2 cols x 4 rows per thread.
// grid (8 jt, 64 ic, 4 bb), block 256 (jp 64 x iq 4). Block covers 128 j x 16 i.
__global__ __launch_bounds__(256) void k_att(const int* __restrict__ adj,
        const float* __restrict__ wv,
        const float* __restrict__ sT, const float* __restrict__ dT,
        short* __restrict__ P, float* __restrict__ denom){
    __shared__ float red[3][64][9];          // [iq-1][jp][h(4)+4..7], pad 9
    int t = threadIdx.x;
    int jp = t & 63, iq = t >> 6;
    int jt = blockIdx.x, ic = blockIdx.y, bb = blockIdx.z;
    int b = bb >> 1, blk = bb & 1;
    int jl = jt * 128 + jp * 2;              // quadrant-local col (2 cols)
    int jg = blk ? jl : HALF + jl;           // global col
    int iloc0 = ic * 16 + iq * 4;            // quadrant-local row base (4 rows)
    int ig0 = (blk ? HALF : 0) + iloc0;
    const int* ap = adj + ((size_t)b * NN + ig0) * NN + jg;
    const float* sp = sT + ((size_t)b * NN + ig0) * HH;
    float4 dv0 = *(const float4*)(dT + ((size_t)b * NN + jg) * HH);
    float4 dv1 = *(const float4*)(dT + ((size_t)b * NN + jg + 1) * HH);
    float da0[4] = {dv0.x, dv0.y, dv0.z, dv0.w};
    float da1[4] = {dv1.x, dv1.y, dv1.z, dv1.w};
    short* Pp = P + ((size_t)(bb * HH) << 20) + (size_t)iloc0 * 1024 + jl;
    float den0[4] = {}, den1[4] = {};
#define ATTBODY(W0, W1) { \
    int2 a2 = *(const int2*)(ap + (size_t)ii * NN); \
    float4 s4 = *(const float4*)(sp + ii * HH); \
    float wm0 = a2.x > 0 ? (W0) : 0.f; \
    float wm1 = a2.y > 0 ? (W1) : 0.f; \
    float sa[4] = {s4.x, s4.y, s4.z, s4.w}; \
    _Pragma("unroll") \
    for(int h = 0; h < HH; h++){ \
        float t0 = sa[h] + da0[h]; t0 = fmaxf(t0, 0.2f * t0); \
        float t1 = sa[h] + da1[h]; t1 = fmaxf(t1, 0.2f * t1); \
        float p0 = __expf(t0) * wm0; \
        float p1 = __expf(t1) * wm1; \
        den0[h] += p0; den1[h] += p1; \
        short2v pk; pk[0] = f2bf(p0); pk[1] = f2bf(p1); \
        *(short2v*)(Pp + ((size_t)h << 20) + (size_t)ii * 1024) = pk; \
    } }
    if(blk){
        const float* wp = wv + ((size_t)b * HALF + iloc0) * HALF + jl;
        #pragma unroll
        for(int ii = 0; ii < 4; ii++){
            float2 w2 = *(const float2*)(wp + (size_t)ii * HALF);
            ATTBODY(w2.x, w2.y)
        }
    } else {
        const float* wp0 = wv + ((size_t)b * HALF + jl) * HALF + iloc0;
        const float* wp1 = wp0 + HALF;
        #pragma unroll
        for(int ii = 0; ii < 4; ii++){
            float w0 = wp0[ii], w1 = wp1[ii];
            ATTBODY(w0, w1)
        }
    }
#undef ATTBODY
    if(iq){
        #pragma unroll
        for(int h = 0; h < HH; h++){
            red[iq - 1][jp][h] = den0[h];
            red[iq - 1][jp][4 + h] = den1[h];
        }
    }
    __syncthreads();
    if(!iq){
        #pragma unroll
        for(int h = 0; h < HH; h++){
            float v0 = den0[h] + red[0][jp][h] + red[1][jp][h] + red[2][jp][h];
            float v1 = den1[h] + red[0][jp][4 + h] + red[1][jp][4 + h] + red[2][jp][4 + h];
            atomicAdd(&denom[((size_t)b * HH + h) * NN + jg], v0);
            atomicAdd(&denom[((size_t)b * HH + h) * NN + jg + 1], v1);
        }
    }
}

// K3: out = ELU((P*inv) @ WhB). Software-pipelined: 1 barrier/k-step, 2-deep
// named-reg prefetch. BM=32, grid (32,4,4)=512 blocks, 4 waves (2m x 2n). (verbatim)
__global__ __launch_bounds__(256) void k_pv(const short* __restrict__ P,
        const float* __restrict__ denom, const short* __restrict__ WhB,
        float* __restrict__ out){
    __shared__ short lds[2][6656];
    __shared__ float invs[1024];
    int t = threadIdx.x;
    int w = t >> 6, lane = t & 63;
    int wm = w >> 1, wn = w & 1;
    int mt = blockIdx.x, h = blockIdx.y, bb = blockIdx.z;
    int b = bb >> 1, blk = bb & 1;
    int sl = b * HH + h;
    const short* Prow = P + ((size_t)(bb * HH + h) << 20);
    size_t Bb2 = ((size_t)sl) * 8;
    int koff = blk ? 0 : 32;
    int col0 = blk ? 0 : HALF;
    const float* npb = denom + (size_t)sl * NN + col0;
    #pragma unroll
    for(int l = 0; l < 4; l++){
        int j = t + l * 256;
        invs[j] = __builtin_amdgcn_rcpf(fmaxf(npb[j], 1e-12f));
    }
    int rowA = t >> 3, c8 = t & 7;
    const short* srcA0 = Prow + (size_t)(mt * 32 + rowA) * 1024 + c8 * 4;
    int m = lane & 15, q = lane >> 4;
    f32x4 acc[4] = {};
    short4v r0A, r0B; short8 r1A, r2A, r1B, r2B;
#define LOADSET(KT, R0, R1, R2) { \
    R0 = *(const short4v*)(srcA0 + (KT) * 32); \
    R1 = *(const short8*)(WhB + ((Bb2 + (t >> 6)) * 64 + koff + (KT)) * 512 + (t & 63) * 8); \
    R2 = *(const short8*)(WhB + ((Bb2 + 4 + (t >> 6)) * 64 + koff + (KT)) * 512 + (t & 63) * 8); }
#define WRITESET(BUF, KT, R0, R1, R2) { \
    float4 iv4 = *(const float4*)&invs[(KT) * 32 + c8 * 4]; \
    short4v rs_; \
    rs_[0] = f2bf(bf2f(R0[0]) * iv4.x); \
    rs_[1] = f2bf(bf2f(R0[1]) * iv4.y); \
    rs_[2] = f2bf(bf2f(R0[2]) * iv4.z); \
    rs_[3] = f2bf(bf2f(R0[3]) * iv4.w); \
    *(short4v*)&lds[BUF][rowA * 40 + c8 * 4] = rs_; \
    *(short8*)&lds[BUF][2560 + (t >> 6) * 512 + (t & 63) * 8] = R1; \
    *(short8*)&lds[BUF][2560 + 2048 + (t >> 6) * 512 + (t & 63) * 8] = R2; }
#define MFMAS(BUF) { \
    short8 af = *(const short8*)&lds[BUF][(wm * 16 + m) * 40 + q * 8]; \
    _Pragma("unroll") \
    for(int ni = 0; ni < 4; ni++){ \
        short8 bf = *(const short8*)&lds[BUF][2560 + (wn * 4 + ni) * 512 + lane * 8]; \
        acc[ni] = __builtin_amdgcn_mfma_f32_16x16x32_bf16(af, bf, acc[ni], 0, 0, 0); \
    } }
    __syncthreads();
    LOADSET(0, r0A, r1A, r2A)
    WRITESET(0, 0, r0A, r1A, r2A)
    LOADSET(1, r0B, r1B, r2B)
    __syncthreads();
    for(int kt = 0; kt < 32; kt += 2){
        if(kt + 2 < 32){ LOADSET(kt + 2, r0A, r1A, r2A) }
        MFMAS(0)
        WRITESET(1, kt + 1, r0B, r1B, r2B)
        __syncthreads();
        if(kt + 3 < 32){ LOADSET(kt + 3, r0B, r1B, r2B) }
        MFMAS(1)
        if(kt + 2 < 32){ WRITESET(0, kt + 2, r0A, r1A, r2A) }
        __syncthreads();
    }
    int rq = lane >> 4, rc = lane & 15;
    int rowg0 = (blk ? HALF : 0) + mt * 32 + wm * 16;
    #pragma unroll
    for(int ni = 0; ni < 4; ni++){
        int f = (wn * 4 + ni) * 16 + rc;
        #pragma unroll
        for(int rg = 0; rg < 4; rg++){
            float v = acc[ni][rg];
            v = v > 0.f ? v : expm1f(v);
            out[((size_t)b * NN + rowg0 + rq * 4 + rg) * (HH * FF) + h * FF + f] = v;
        }
    }
#undef LOADSET
#undef WRITESET
#undef MFMAS
}

extern "C" void kernel_launch(void* const* d_in, const int* in_sizes, int n_in,
                              void* d_out, int out_size, void* d_ws, size_t ws_size,
                              hipStream_t stream){
    const float* x   = (const float*)d_in[0];
    const float* wv  = (const float*)d_in[1];
    const float* W   = (const float*)d_in[2];
    const float* a   = (const float*)d_in[3];
    const int*   adj = (const int*)d_in[4];
    float* out = (float*)d_out;

    char* ws = (char*)d_ws;
    short* P     = (short*)ws;                   // 33,554,432 B
    short* WhB   = (short*)(ws + 33554432);      //  4,194,304 B
    float* sT    = (float*)(ws + 37748736);      //     65,536 B
    float* dT    = (float*)(ws + 37814272);      //     65,536 B
    float* denom = (float*)(ws + 37879808);      //     65,536 B

    k_whmm<<<dim3(32, HH, BB), 256, 0, stream>>>(x, W, a, WhB, sT, dT, denom);
    k_att<<<dim3(8, 64, 4), 256, 0, stream>>>(adj, wv, sT, dT, P, denom);
    k_pv<<<dim3(32, HH, 4), 256, 0, stream>>>(P, denom, WhB, out);
}

// Round 16
// 45.363 us; speedup vs baseline: 1.0571x; 1.0571x over previous
//
#include <hip/hip_runtime.h>
#include <hip/hip_bf16.h>
#include <math.h>

#define BB 2
#define NN 2048
#define FF 128
#define HH 4
#define HALF 1024

typedef __attribute__((ext_vector_type(8))) short short8;
typedef __attribute__((ext_vector_type(4))) short short4v;
typedef __attribute__((ext_vector_type(4))) float f32x4;

__device__ __forceinline__ short f2bf(float f){
    __hip_bfloat16 h = __float2bfloat16(f);
    return *reinterpret_cast<short*>(&h);
}
__device__ __forceinline__ float bf2f(short v){
    __hip_bfloat16 h = *reinterpret_cast<__hip_bfloat16*>(&v);
    return __bfloat162float(h);
}

// K1: x @ W[h] via MFMA -> WhB (bf16 B-fragment layout, UNSCALED) + sT/dT + denom zero.
// W staged TRANSPOSED (wsT[n][k], 136-short rows) so B-frags read as contiguous b128.
// grid (32, 4, 2), block 256 = 4 waves (wm=w>>1, wn=w&1).
__global__ __launch_bounds__(256) void k_whmm(const float* __restrict__ x,
        const float* __restrict__ W, const float* __restrict__ a,
        short* __restrict__ WhB, float* __restrict__ sT, float* __restrict__ dT,
        float* __restrict__ denom){
    __shared__ short xs[64 * 136];
    __shared__ short wsT[128 * 136];
    __shared__ float red_s[2][64], red_d[2][64];
    int t = threadIdx.x;
    int w = t >> 6, lane = t & 63;
    int wm = w >> 1, wn = w & 1;
    int n0 = blockIdx.x * 64;
    int h = blockIdx.y, b = blockIdx.z;
    int sl = b * HH + h;
    int flat = blockIdx.x + 32 * (blockIdx.y + HH * blockIdx.z);
    if(t < 64) denom[flat * 64 + t] = 0.f;
    const float* xb = x + ((size_t)b * NN + n0) * FF;
    #pragma unroll
    for(int l = 0; l < 8; l++){
        int flat4 = t + l * 256;
        int row = flat4 >> 5, col4 = flat4 & 31;
        float4 v = *(const float4*)(xb + (size_t)row * FF + col4 * 4);
        short* dst = &xs[row * 136 + col4 * 4];
        dst[0] = f2bf(v.x); dst[1] = f2bf(v.y); dst[2] = f2bf(v.z); dst[3] = f2bf(v.w);
    }
    // stage W[h] TRANSPOSED: wsT[n * 136 + k] = W[k][n]
    const float* Wb = W + (size_t)h * FF * FF;
    #pragma unroll
    for(int l = 0; l < 16; l++){
        int flat4 = t + l * 256;
        int row = flat4 >> 5, col4 = flat4 & 31;   // row = k, col4*4.. = n
        float4 v = *(const float4*)(Wb + (size_t)row * FF + col4 * 4);
        wsT[(col4 * 4 + 0) * 136 + row] = f2bf(v.x);
        wsT[(col4 * 4 + 1) * 136 + row] = f2bf(v.y);
        wsT[(col4 * 4 + 2) * 136 + row] = f2bf(v.z);
        wsT[(col4 * 4 + 3) * 136 + row] = f2bf(v.w);
    }
    __syncthreads();
    int m = lane & 15, q = lane >> 4;
    f32x4 acc[2][4] = {};
    #pragma unroll
    for(int ks = 0; ks < 4; ks++){
        short8 af[2];
        #pragma unroll
        for(int mi = 0; mi < 2; mi++)
            af[mi] = *(const short8*)&xs[(wm * 32 + mi * 16 + m) * 136 + ks * 32 + q * 8];
        short8 bf[4];
        #pragma unroll
        for(int ni = 0; ni < 4; ni++)
            bf[ni] = *(const short8*)&wsT[(wn * 64 + ni * 16 + m) * 136 + ks * 32 + q * 8];
        #pragma unroll
        for(int mi = 0; mi < 2; mi++)
            #pragma unroll
            for(int ni = 0; ni < 4; ni++)
                acc[mi][ni] = __builtin_amdgcn_mfma_f32_16x16x32_bf16(af[mi], bf[ni], acc[mi][ni], 0, 0, 0);
    }
    float asrc[4], adst[4];
    const float* ah = a + (size_t)h * 2 * FF;
    #pragma unroll
    for(int ni = 0; ni < 4; ni++){
        int col = wn * 64 + ni * 16 + m;
        asrc[ni] = ah[col];
        adst[ni] = ah[FF + col];
    }
    #pragma unroll
    for(int mi = 0; mi < 2; mi++){
        #pragma unroll
        for(int rg = 0; rg < 4; rg++){
            float ps = 0.f, pd = 0.f;
            #pragma unroll
            for(int ni = 0; ni < 4; ni++){
                ps += acc[mi][ni][rg] * asrc[ni];
                pd += acc[mi][ni][rg] * adst[ni];
            }
            #pragma unroll
            for(int msk = 8; msk >= 1; msk >>= 1){
                ps += __shfl_xor(ps, msk);
                pd += __shfl_xor(pd, msk);
            }
            if(m == 0){
                int row = wm * 32 + mi * 16 + q * 4 + rg;
                red_s[wn][row] = ps;
                red_d[wn][row] = pd;
            }
        }
    }
    __syncthreads();
    short* cs = xs;
    #pragma unroll
    for(int mi = 0; mi < 2; mi++){
        #pragma unroll
        for(int ni = 0; ni < 4; ni++){
            int col = wn * 64 + ni * 16 + m;
            #pragma unroll
            for(int rg = 0; rg < 4; rg++){
                int row = wm * 32 + mi * 16 + q * 4 + rg;
                cs[row * 130 + col] = f2bf(acc[mi][ni][rg]);
            }
        }
    }
    if(t < 64){
        int n = n0 + t;
        sT[((size_t)b * NN + n) * HH + h] = red_s[0][t] + red_s[1][t];
        dT[((size_t)b * NN + n) * HH + h] = red_d[0][t] + red_d[1][t];
    }
    __syncthreads();
    #pragma unroll
    for(int fi = 0; fi < 4; fi++){
        int fragId = w * 4 + fi;
        int ktg = fragId >> 3, nt = fragId & 7;
        short8 pk;
        #pragma unroll
        for(int e = 0; e < 8; e++)
            pk[e] = cs[(ktg * 32 + q * 8 + e) * 130 + nt * 16 + m];
        *(short8*)(WhB + (((size_t)sl * 8 + nt) * 64 + blockIdx.x * 2 + ktg) * 512 + lane * 8) = pk;
    }
}

// K2: ROW-MAJOR streaming attention (8 rows/thread). grid (8, 64, 4), block 256.
// (verbatim round 14 — proven shape: 1 col x 8 rows)
__global__ __launch_bounds__(256) void k_att(const int* __restrict__ adj,
        const float* __restrict__ wv,
        const float* __restrict__ sT, const float* __restrict__ dT,
        short* __restrict__ P, float* __restrict__ denom){
    __shared__ float red[HH][128];
    int t = threadIdx.x;
    int jlane = t & 127, ihalf = t >> 7;
    int jt = blockIdx.x, ic = blockIdx.y, bb = blockIdx.z;
    int b = bb >> 1, blk = bb & 1;
    int jl = jt * 128 + jlane;
    int jg = blk ? jl : HALF + jl;
    int iloc0 = ic * 16 + ihalf * 8;
    int ig0 = (blk ? HALF : 0) + iloc0;
    const int* ap = adj + ((size_t)b * NN + ig0) * NN + jg;
    const float* sp = sT + ((size_t)b * NN + ig0) * HH;
    float4 dv4 = *(const float4*)(dT + ((size_t)b * NN + jg) * HH);
    float da[4] = {dv4.x, dv4.y, dv4.z, dv4.w};
    short* Pp = P + ((size_t)(bb * HH) << 20) + (size_t)iloc0 * 1024 + jl;
    float den[HH] = {};
#define ATTLOOP(WPTR, WSTRIDE) \
    _Pragma("unroll 4") \
    for(int ii = 0; ii < 8; ii++){ \
        int av = ap[(size_t)ii * NN]; \
        float wq = (WPTR)[(size_t)ii * (WSTRIDE)]; \
        float4 s4 = *(const float4*)(sp + ii * HH); \
        float wmv = av > 0 ? wq : 0.f; \
        float sa[4] = {s4.x, s4.y, s4.z, s4.w}; \
        _Pragma("unroll") \
        for(int h = 0; h < HH; h++){ \
            float tt = sa[h] + da[h]; \
            tt = tt > 0.f ? tt : 0.2f * tt; \
            float pe = __expf(tt) * wmv; \
            den[h] += pe; \
            Pp[((size_t)h << 20) + (size_t)ii * 1024] = f2bf(pe); \
        } \
    }
    if(blk){
        const float* wp = wv + ((size_t)b * HALF + iloc0) * HALF + jl;
        ATTLOOP(wp, HALF)
    } else {
        const float* wp = wv + ((size_t)b * HALF + jl) * HALF + iloc0;
        ATTLOOP(wp, 1)
    }
#undef ATTLOOP
    if(ihalf){
        #pragma unroll
        for(int h = 0; h < HH; h++) red[h][jlane] = den[h];
    }
    __syncthreads();
    if(!ihalf){
        #pragma unroll
        for(int h = 0; h < HH; h++)
            atomicAdd(&denom[((size_t)b * HH + h) * NN + jg], den[h] + red[h][jlane]);
    }
}

// K3: out = ELU((P*inv) @ WhB). Software-pipelined: 1 barrier/k-step, 2-deep
// named-reg prefetch. BM=32, grid (32,4,4)=512 blocks, 4 waves (2m x 2n). (verbatim round 14)
__global__ __launch_bounds__(256) void k_pv(const short* __restrict__ P,
        const float* __restrict__ denom, const short* __restrict__ WhB,
        float* __restrict__ out){
    __shared__ short lds[2][6656];
    __shared__ float invs[1024];
    int t = threadIdx.x;
    int w = t >> 6, lane = t & 63;
    int wm = w >> 1, wn = w & 1;
    int mt = blockIdx.x, h = blockIdx.y, bb = blockIdx.z;
    int b = bb >> 1, blk = bb & 1;
    int sl = b * HH + h;
    const short* Prow = P + ((size_t)(bb * HH + h) << 20);
    size_t Bb2 = ((size_t)sl) * 8;
    int koff = blk ? 0 : 32;
    int col0 = blk ? 0 : HALF;
    const float* npb = denom + (size_t)sl * NN + col0;
    #pragma unroll
    for(int l = 0; l < 4; l++){
        int j = t + l * 256;
        invs[j] = __builtin_amdgcn_rcpf(fmaxf(npb[j], 1e-12f));
    }
    int rowA = t >> 3, c8 = t & 7;
    const short* srcA0 = Prow + (size_t)(mt * 32 + rowA) * 1024 + c8 * 4;
    int m = lane & 15, q = lane >> 4;
    f32x4 acc[4] = {};
    short4v r0A, r0B; short8 r1A, r2A, r1B, r2B;
#define LOADSET(KT, R0, R1, R2) { \
    R0 = *(const short4v*)(srcA0 + (KT) * 32); \
    R1 = *(const short8*)(WhB + ((Bb2 + (t >> 6)) * 64 + koff + (KT)) * 512 + (t & 63) * 8); \
    R2 = *(const short8*)(WhB + ((Bb2 + 4 + (t >> 6)) * 64 + koff + (KT)) * 512 + (t & 63) * 8); }
#define WRITESET(BUF, KT, R0, R1, R2) { \
    float4 iv4 = *(const float4*)&invs[(KT) * 32 + c8 * 4]; \
    short4v rs_; \
    rs_[0] = f2bf(bf2f(R0[0]) * iv4.x); \
    rs_[1] = f2bf(bf2f(R0[1]) * iv4.y); \
    rs_[2] = f2bf(bf2f(R0[2]) * iv4.z); \
    rs_[3] = f2bf(bf2f(R0[3]) * iv4.w); \
    *(short4v*)&lds[BUF][rowA * 40 + c8 * 4] = rs_; \
    *(short8*)&lds[BUF][2560 + (t >> 6) * 512 + (t & 63) * 8] = R1; \
    *(short8*)&lds[BUF][2560 + 2048 + (t >> 6) * 512 + (t & 63) * 8] = R2; }
#define MFMAS(BUF) { \
    short8 af = *(const short8*)&lds[BUF][(wm * 16 + m) * 40 + q * 8]; \
    _Pragma("unroll") \
    for(int ni = 0; ni < 4; ni++){ \
        short8 bf = *(const short8*)&lds[BUF][2560 + (wn * 4 + ni) * 512 + lane * 8]; \
        acc[ni] = __builtin_amdgcn_mfma_f32_16x16x32_bf16(af, bf, acc[ni], 0, 0, 0); \
    } }
    __syncthreads();
    LOADSET(0, r0A, r1A, r2A)
    WRITESET(0, 0, r0A, r1A, r2A)
    LOADSET(1, r0B, r1B, r2B)
    __syncthreads();
    for(int kt = 0; kt < 32; kt += 2){
        if(kt + 2 < 32){ LOADSET(kt + 2, r0A, r1A, r2A) }
        MFMAS(0)
        WRITESET(1, kt + 1, r0B, r1B, r2B)
        __syncthreads();
        if(kt + 3 < 32){ LOADSET(kt + 3, r0B, r1B, r2B) }
        MFMAS(1)
        if(kt + 2 < 32){ WRITESET(0, kt + 2, r0A, r1A, r2A) }
        __syncthreads();
    }
    int rq = lane >> 4, rc = lane & 15;
    int rowg0 = (blk ? HALF : 0) + mt * 32 + wm * 16;
    #pragma unroll
    for(int ni = 0; ni < 4; ni++){
        int f = (wn * 4 + ni) * 16 + rc;
        #pragma unroll
        for(int rg = 0; rg < 4; rg++){
            float v = acc[ni][rg];
            v = v > 0.f ? v : expm1f(v);
            out[((size_t)b * NN + rowg0 + rq * 4 + rg) * (HH * FF) + h * FF + f] = v;
        }
    }
#undef LOADSET
#undef WRITESET
#undef MFMAS
}

extern "C" void kernel_launch(void* const* d_in, const int* in_sizes, int n_in,
                              void* d_out, int out_size, void* d_ws, size_t ws_size,
                              hipStream_t stream){
    const float* x   = (const float*)d_in[0];
    const float* wv  = (const float*)d_in[1];
    const float* W   = (const float*)d_in[2];
    const float* a   = (const float*)d_in[3];
    const int*   adj = (const int*)d_in[4];
    float* out = (float*)d_out;

    char* ws = (char*)d_ws;
    short* P     = (short*)ws;                   // 33,554,432 B
    short* WhB   = (short*)(ws + 33554432);      //  4,194,304 B
    float* sT    = (float*)(ws + 37748736);      //     65,536 B
    float* dT    = (float*)(ws + 37814272);      //     65,536 B
    float* denom = (float*)(ws + 37879808);      //     65,536 B

    k_whmm<<<dim3(32, HH, BB), 256, 0, stream>>>(x, W, a, WhB, sT, dT, denom);
    k_att<<<dim3(8, 64, 4), 256, 0, stream>>>(adj, wv, sT, dT, P, denom);
    k_pv<<<dim3(32, HH, 4), 256, 0, stream>>>(P, denom, WhB, out);
}

// Round 17
// 43.054 us; speedup vs baseline: 1.1138x; 1.0536x over previous
//
#include <hip/hip_runtime.h>
#include <hip/hip_bf16.h>
#include <math.h>

#define BB 2
#define NN 2048
#define FF 128
#define HH 4
#define HALF 1024

typedef __attribute__((ext_vector_type(8))) short short8;
typedef __attribute__((ext_vector_type(4))) short short4v;
typedef __attribute__((ext_vector_type(4))) float f32x4;

__device__ __forceinline__ short f2bf(float f){
    __hip_bfloat16 h = __float2bfloat16(f);
    return *reinterpret_cast<short*>(&h);
}
__device__ __forceinline__ float bf2f(short v){
    __hip_bfloat16 h = *reinterpret_cast<__hip_bfloat16*>(&v);
    return __bfloat162float(h);
}

// K1: x @ W[h] via MFMA -> WhB (bf16 B-fragment layout, UNSCALED) + sT/dT + denom zero.
// grid (32, 4, 2), block 256 = 4 waves (wm=w>>1, wn=w&1). (round-14 verified best)
__global__ __launch_bounds__(256) void k_whmm(const float* __restrict__ x,
        const float* __restrict__ W, const float* __restrict__ a,
        short* __restrict__ WhB, float* __restrict__ sT, float* __restrict__ dT,
        float* __restrict__ denom){
    __shared__ short xs[64 * 136];
    __shared__ short ws_[128 * 130];
    __shared__ float red_s[2][64], red_d[2][64];
    int t = threadIdx.x;
    int w = t >> 6, lane = t & 63;
    int wm = w >> 1, wn = w & 1;
    int n0 = blockIdx.x * 64;
    int h = blockIdx.y, b = blockIdx.z;
    int sl = b * HH + h;
    int flat = blockIdx.x + 32 * (blockIdx.y + HH * blockIdx.z);
    if(t < 64) denom[flat * 64 + t] = 0.f;
    const float* xb = x + ((size_t)b * NN + n0) * FF;
    #pragma unroll
    for(int l = 0; l < 8; l++){
        int flat4 = t + l * 256;
        int row = flat4 >> 5, col4 = flat4 & 31;
        float4 v = *(const float4*)(xb + (size_t)row * FF + col4 * 4);
        short* dst = &xs[row * 136 + col4 * 4];
        dst[0] = f2bf(v.x); dst[1] = f2bf(v.y); dst[2] = f2bf(v.z); dst[3] = f2bf(v.w);
    }
    const float* Wb = W + (size_t)h * FF * FF;
    #pragma unroll
    for(int l = 0; l < 16; l++){
        int flat4 = t + l * 256;
        int row = flat4 >> 5, col4 = flat4 & 31;
        float4 v = *(const float4*)(Wb + (size_t)row * FF + col4 * 4);
        short* dst = &ws_[row * 130 + col4 * 4];
        dst[0] = f2bf(v.x); dst[1] = f2bf(v.y); dst[2] = f2bf(v.z); dst[3] = f2bf(v.w);
    }
    __syncthreads();
    int m = lane & 15, q = lane >> 4;
    f32x4 acc[2][4] = {};
    #pragma unroll
    for(int ks = 0; ks < 4; ks++){
        short8 af[2];
        #pragma unroll
        for(int mi = 0; mi < 2; mi++)
            af[mi] = *(const short8*)&xs[(wm * 32 + mi * 16 + m) * 136 + ks * 32 + q * 8];
        short8 bf[4];
        #pragma unroll
        for(int ni = 0; ni < 4; ni++){
            #pragma unroll
            for(int e = 0; e < 8; e++)
                bf[ni][e] = ws_[(ks * 32 + q * 8 + e) * 130 + wn * 64 + ni * 16 + m];
        }
        #pragma unroll
        for(int mi = 0; mi < 2; mi++)
            #pragma unroll
            for(int ni = 0; ni < 4; ni++)
                acc[mi][ni] = __builtin_amdgcn_mfma_f32_16x16x32_bf16(af[mi], bf[ni], acc[mi][ni], 0, 0, 0);
    }
    float asrc[4], adst[4];
    const float* ah = a + (size_t)h * 2 * FF;
    #pragma unroll
    for(int ni = 0; ni < 4; ni++){
        int col = wn * 64 + ni * 16 + m;
        asrc[ni] = ah[col];
        adst[ni] = ah[FF + col];
    }
    #pragma unroll
    for(int mi = 0; mi < 2; mi++){
        #pragma unroll
        for(int rg = 0; rg < 4; rg++){
            float ps = 0.f, pd = 0.f;
            #pragma unroll
            for(int ni = 0; ni < 4; ni++){
                ps += acc[mi][ni][rg] * asrc[ni];
                pd += acc[mi][ni][rg] * adst[ni];
            }
            #pragma unroll
            for(int msk = 8; msk >= 1; msk >>= 1){
                ps += __shfl_xor(ps, msk);
                pd += __shfl_xor(pd, msk);
            }
            if(m == 0){
                int row = wm * 32 + mi * 16 + q * 4 + rg;
                red_s[wn][row] = ps;
                red_d[wn][row] = pd;
            }
        }
    }
    __syncthreads();
    short* cs = xs;
    #pragma unroll
    for(int mi = 0; mi < 2; mi++){
        #pragma unroll
        for(int ni = 0; ni < 4; ni++){
            int col = wn * 64 + ni * 16 + m;
            #pragma unroll
            for(int rg = 0; rg < 4; rg++){
                int row = wm * 32 + mi * 16 + q * 4 + rg;
                cs[row * 130 + col] = f2bf(acc[mi][ni][rg]);
            }
        }
    }
    if(t < 64){
        int n = n0 + t;
        sT[((size_t)b * NN + n) * HH + h] = red_s[0][t] + red_s[1][t];
        dT[((size_t)b * NN + n) * HH + h] = red_d[0][t] + red_d[1][t];
    }
    __syncthreads();
    #pragma unroll
    for(int fi = 0; fi < 4; fi++){
        int fragId = w * 4 + fi;
        int ktg = fragId >> 3, nt = fragId & 7;
        short8 pk;
        #pragma unroll
        for(int e = 0; e < 8; e++)
            pk[e] = cs[(ktg * 32 + q * 8 + e) * 130 + nt * 16 + m];
        *(short8*)(WhB + (((size_t)sl * 8 + nt) * 64 + blockIdx.x * 2 + ktg) * 512 + lane * 8) = pk;
    }
}

// K2: ROW-MAJOR streaming attention (8 rows/thread). grid (8, 64, 4), block 256.
// (round-14 verified best — proven shape: 1 col x 8 rows)
__global__ __launch_bounds__(256) void k_att(const int* __restrict__ adj,
        const float* __restrict__ wv,
        const float* __restrict__ sT, const float* __restrict__ dT,
        short* __restrict__ P, float* __restrict__ denom){
    __shared__ float red[HH][128];
    int t = threadIdx.x;
    int jlane = t & 127, ihalf = t >> 7;
    int jt = blockIdx.x, ic = blockIdx.y, bb = blockIdx.z;
    int b = bb >> 1, blk = bb & 1;
    int jl = jt * 128 + jlane;
    int jg = blk ? jl : HALF + jl;
    int iloc0 = ic * 16 + ihalf * 8;
    int ig0 = (blk ? HALF : 0) + iloc0;
    const int* ap = adj + ((size_t)b * NN + ig0) * NN + jg;
    const float* sp = sT + ((size_t)b * NN + ig0) * HH;
    float4 dv4 = *(const float4*)(dT + ((size_t)b * NN + jg) * HH);
    float da[4] = {dv4.x, dv4.y, dv4.z, dv4.w};
    short* Pp = P + ((size_t)(bb * HH) << 20) + (size_t)iloc0 * 1024 + jl;
    float den[HH] = {};
#define ATTLOOP(WPTR, WSTRIDE) \
    _Pragma("unroll 4") \
    for(int ii = 0; ii < 8; ii++){ \
        int av = ap[(size_t)ii * NN]; \
        float wq = (WPTR)[(size_t)ii * (WSTRIDE)]; \
        float4 s4 = *(const float4*)(sp + ii * HH); \
        float wmv = av > 0 ? wq : 0.f; \
        float sa[4] = {s4.x, s4.y, s4.z, s4.w}; \
        _Pragma("unroll") \
        for(int h = 0; h < HH; h++){ \
            float tt = sa[h] + da[h]; \
            tt = tt > 0.f ? tt : 0.2f * tt; \
            float pe = __expf(tt) * wmv; \
            den[h] += pe; \
            Pp[((size_t)h << 20) + (size_t)ii * 1024] = f2bf(pe); \
        } \
    }
    if(blk){
        const float* wp = wv + ((size_t)b * HALF + iloc0) * HALF + jl;
        ATTLOOP(wp, HALF)
    } else {
        const float* wp = wv + ((size_t)b * HALF + jl) * HALF + iloc0;
        ATTLOOP(wp, 1)
    }
#undef ATTLOOP
    if(ihalf){
        #pragma unroll
        for(int h = 0; h < HH; h++) red[h][jlane] = den[h];
    }
    __syncthreads();
    if(!ihalf){
        #pragma unroll
        for(int h = 0; h < HH; h++)
            atomicAdd(&denom[((size_t)b * HH + h) * NN + jg], den[h] + red[h][jlane]);
    }
}

// K3: out = ELU((P*inv) @ WhB). Software-pipelined: 1 barrier/k-step, 2-deep
// named-reg prefetch. BM=32, grid (32,4,4)=512 blocks, 4 waves (2m x 2n).
// (round-14 verified best)
__global__ __launch_bounds__(256) void k_pv(const short* __restrict__ P,
        const float* __restrict__ denom, const short* __restrict__ WhB,
        float* __restrict__ out){
    __shared__ short lds[2][6656];
    __shared__ float invs[1024];
    int t = threadIdx.x;
    int w = t >> 6, lane = t & 63;
    int wm = w >> 1, wn = w & 1;
    int mt = blockIdx.x, h = blockIdx.y, bb = blockIdx.z;
    int b = bb >> 1, blk = bb & 1;
    int sl = b * HH + h;
    const short* Prow = P + ((size_t)(bb * HH + h) << 20);
    size_t Bb2 = ((size_t)sl) * 8;
    int koff = blk ? 0 : 32;
    int col0 = blk ? 0 : HALF;
    const float* npb = denom + (size_t)sl * NN + col0;
    #pragma unroll
    for(int l = 0; l < 4; l++){
        int j = t + l * 256;
        invs[j] = __builtin_amdgcn_rcpf(fmaxf(npb[j], 1e-12f));
    }
    int rowA = t >> 3, c8 = t & 7;
    const short* srcA0 = Prow + (size_t)(mt * 32 + rowA) * 1024 + c8 * 4;
    int m = lane & 15, q = lane >> 4;
    f32x4 acc[4] = {};
    short4v r0A, r0B; short8 r1A, r2A, r1B, r2B;
#define LOADSET(KT, R0, R1, R2) { \
    R0 = *(const short4v*)(srcA0 + (KT) * 32); \
    R1 = *(const short8*)(WhB + ((Bb2 + (t >> 6)) * 64 + koff + (KT)) * 512 + (t & 63) * 8); \
    R2 = *(const short8*)(WhB + ((Bb2 + 4 + (t >> 6)) * 64 + koff + (KT)) * 512 + (t & 63) * 8); }
#define WRITESET(BUF, KT, R0, R1, R2) { \
    float4 iv4 = *(const float4*)&invs[(KT) * 32 + c8 * 4]; \
    short4v rs_; \
    rs_[0] = f2bf(bf2f(R0[0]) * iv4.x); \
    rs_[1] = f2bf(bf2f(R0[1]) * iv4.y); \
    rs_[2] = f2bf(bf2f(R0[2]) * iv4.z); \
    rs_[3] = f2bf(bf2f(R0[3]) * iv4.w); \
    *(short4v*)&lds[BUF][rowA * 40 + c8 * 4] = rs_; \
    *(short8*)&lds[BUF][2560 + (t >> 6) * 512 + (t & 63) * 8] = R1; \
    *(short8*)&lds[BUF][2560 + 2048 + (t >> 6) * 512 + (t & 63) * 8] = R2; }
#define MFMAS(BUF) { \
    short8 af = *(const short8*)&lds[BUF][(wm * 16 + m) * 40 + q * 8]; \
    _Pragma("unroll") \
    for(int ni = 0; ni < 4; ni++){ \
        short8 bf = *(const short8*)&lds[BUF][2560 + (wn * 4 + ni) * 512 + lane * 8]; \
        acc[ni] = __builtin_amdgcn_mfma_f32_16x16x32_bf16(af, bf, acc[ni], 0, 0, 0); \
    } }
    __syncthreads();
    LOADSET(0, r0A, r1A, r2A)
    WRITESET(0, 0, r0A, r1A, r2A)
    LOADSET(1, r0B, r1B, r2B)
    __syncthreads();
    for(int kt = 0; kt < 32; kt += 2){
        if(kt + 2 < 32){ LOADSET(kt + 2, r0A, r1A, r2A) }
        MFMAS(0)
        WRITESET(1, kt + 1, r0B, r1B, r2B)
        __syncthreads();
        if(kt + 3 < 32){ LOADSET(kt + 3, r0B, r1B, r2B) }
        MFMAS(1)
        if(kt + 2 < 32){ WRITESET(0, kt + 2, r0A, r1A, r2A) }
        __syncthreads();
    }
    int rq = lane >> 4, rc = lane & 15;
    int rowg0 = (blk ? HALF : 0) + mt * 32 + wm * 16;
    #pragma unroll
    for(int ni = 0; ni < 4; ni++){
        int f = (wn * 4 + ni) * 16 + rc;
        #pragma unroll
        for(int rg = 0; rg < 4; rg++){
            float v = acc[ni][rg];
            v = v > 0.f ? v : expm1f(v);
            out[((size_t)b * NN + rowg0 + rq * 4 + rg) * (HH * FF) + h * FF + f] = v;
        }
    }
#undef LOADSET
#undef WRITESET
#undef MFMAS
}

extern "C" void kernel_launch(void* const* d_in, const int* in_sizes, int n_in,
                              void* d_out, int out_size, void* d_ws, size_t ws_size,
                              hipStream_t stream){
    const float* x   = (const float*)d_in[0];
    const float* wv  = (const float*)d_in[1];
    const float* W   = (const float*)d_in[2];
    const float* a   = (const float*)d_in[3];
    const int*   adj = (const int*)d_in[4];
    float* out = (float*)d_out;

    char* ws = (char*)d_ws;
    short* P     = (short*)ws;                   // 33,554,432 B
    short* WhB   = (short*)(ws + 33554432);      //  4,194,304 B
    float* sT    = (float*)(ws + 37748736);      //     65,536 B
    float* dT    = (float*)(ws + 37814272);      //     65,536 B
    float* denom = (float*)(ws + 37879808);      //     65,536 B

    k_whmm<<<dim3(32, HH, BB), 256, 0, stream>>>(x, W, a, WhB, sT, dT, denom);
    k_att<<<dim3(8, 64, 4), 256, 0, stream>>>(adj, wv, sT, dT, P, denom);
    k_pv<<<dim3(32, HH, 4), 256, 0, stream>>>(P, denom, WhB, out);
}